// Round 5
// baseline (911.638 us; speedup 1.0000x reference)
//
#include <hip/hip_runtime.h>
#include <hip/hip_bf16.h>

// GCN forward: out = (A' @ relu((A' @ X) @ W1^T) * mask) @ W2^T
// restructured as:  B1 = A'X;  B1 = relu(B1 W1^T)*mask;  B2 = B1 W2^T;  out = A' B2
// A' applied via CSR built on-device each launch (ws is re-poisoned every call).

#define WAVE 64

// ---------------- CSR build ----------------

__global__ __launch_bounds__(256) void k_hist(const int* __restrict__ row,
                                              int* __restrict__ counts, int E) {
    int i = blockIdx.x * blockDim.x + threadIdx.x;
    int stride = gridDim.x * blockDim.x;
    for (; i < E; i += stride) atomicAdd(&counts[row[i]], 1);
}

__global__ __launch_bounds__(256) void k_part(const int* __restrict__ counts,
                                              int* __restrict__ partial, int n) {
    __shared__ int s[256];
    int t = threadIdx.x;
    int i = blockIdx.x * 256 + t;
    s[t] = (i < n) ? counts[i] : 0;
    __syncthreads();
    for (int off = 128; off > 0; off >>= 1) {
        if (t < off) s[t] += s[t + off];
        __syncthreads();
    }
    if (t == 0) partial[blockIdx.x] = s[0];
}

// single block: exclusive-scan partial[np] in place; starts[N] = total
__global__ __launch_bounds__(512) void k_scanpart(int* __restrict__ partial, int np,
                                                  int* __restrict__ starts, int N) {
    __shared__ int s[512];
    int t = threadIdx.x;
    int v = (t < np) ? partial[t] : 0;
    s[t] = v;
    __syncthreads();
    for (int off = 1; off < 512; off <<= 1) {
        int x = (t >= off) ? s[t - off] : 0;
        __syncthreads();
        s[t] += x;
        __syncthreads();
    }
    if (t < np) partial[t] = s[t] - v;   // exclusive
    if (t == 0) starts[N] = s[511];      // total = E
}

__global__ __launch_bounds__(256) void k_starts(const int* __restrict__ counts,
                                                const int* __restrict__ partial,
                                                int* __restrict__ starts,
                                                int* __restrict__ cursor, int n) {
    __shared__ int s[256];
    int t = threadIdx.x;
    int b = blockIdx.x;
    int i = b * 256 + t;
    int v = (i < n) ? counts[i] : 0;
    s[t] = v;
    __syncthreads();
    for (int off = 1; off < 256; off <<= 1) {
        int x = (t >= off) ? s[t - off] : 0;
        __syncthreads();
        s[t] += x;
        __syncthreads();
    }
    if (i < n) {
        int e = partial[b] + s[t] - v;
        starts[i] = e;
        cursor[i] = e;   // cursor aliases counts; safe: each i read+written by same thread
    }
}

__global__ __launch_bounds__(256) void k_scatter(const int* __restrict__ row,
                                                 const int* __restrict__ col,
                                                 const float* __restrict__ vals,
                                                 int* __restrict__ cursor,
                                                 int* __restrict__ adj_col,
                                                 float* __restrict__ adj_val, int E) {
    int i = blockIdx.x * blockDim.x + threadIdx.x;
    int stride = gridDim.x * blockDim.x;
    for (; i < E; i += stride) {
        int r = row[i];
        int p = atomicAdd(&cursor[r], 1);
        adj_col[p] = col[i];
        adj_val[p] = vals[i];
    }
}

// ---------------- SpMM (gather form; A symmetric so CSR == CSC) ----------------
// block = 256 threads = (256/D) row-subgroups; each subgroup: one row,
// per neighbor one coalesced D*4-byte read of src row.

template <int D>
__global__ __launch_bounds__(256) void k_spmm(const int* __restrict__ starts,
                                              const int* __restrict__ adj_col,
                                              const float* __restrict__ adj_val,
                                              const float* __restrict__ src,
                                              float* __restrict__ dst, int n) {
    constexpr int RPB = 256 / D;
    const int rr = threadIdx.x / D;
    const int d = threadIdx.x % D;
    const int r = blockIdx.x * RPB + rr;
    if (r >= n) return;
    const int j1 = starts[r + 1];
    int j = starts[r];
    float acc = 0.f;
    // light software pipeline: prefetch next (c,v) while gathering current
    int c = 0;
    float v = 0.f;
    if (j < j1) { c = adj_col[j]; v = adj_val[j]; }
    for (; j < j1;) {
        int jn = j + 1;
        int cn = 0;
        float vn = 0.f;
        if (jn < j1) { cn = adj_col[jn]; vn = adj_val[jn]; }
        acc += v * src[(size_t)c * D + d];
        c = cn;
        v = vn;
        j = jn;
    }
    dst[(size_t)r * D + d] = acc;
}

// ---------------- dense GEMM: dst[n,DOUT] = src[n,128] @ W[DOUT,128]^T ----------------
// W staged transposed in LDS (Wt[k][h]) so the lane-varying operand read is a
// conflict-free row-sweep ds_read_b128; H reads are wave-broadcast (free-ish).
// KS-way K-split staging keeps static LDS at 48KB -> 3 blocks/CU.

template <int DOUT, int KS, int RB, bool FUSE>
__global__ __launch_bounds__(256) void k_gemm(const float* __restrict__ src,
                                              const float* __restrict__ W,
                                              const float* __restrict__ mask,
                                              float* __restrict__ dst, int n) {
    constexpr int H4 = DOUT / 4;       // float4 groups along output dim
    constexpr int RG = 256 / H4;       // row groups
    constexpr int ROWS = RG * RB;      // rows per block (32)
    constexpr int KR = 128 / KS;       // k-rows resident per split
    __shared__ float Wt[KR * DOUT];
    __shared__ float Ht[ROWS * 128];

    const int t = threadIdx.x;
    const int r0 = blockIdx.x * ROWS;

    // stage H tile (coalesced float4 reads, conflict-free b128 LDS writes)
    float4* Ht4 = reinterpret_cast<float4*>(Ht);
    for (int idx = t; idx < ROWS * 32; idx += 256) {
        int rr = idx >> 5, kq = idx & 31;
        int r = r0 + rr;
        float4 v = make_float4(0.f, 0.f, 0.f, 0.f);
        if (r < n) v = reinterpret_cast<const float4*>(src)[(size_t)r * 32 + kq];
        Ht4[idx] = v;
    }

    const int h4 = t % H4;
    const int rg = t / H4;
    float acc[RB][4];
#pragma unroll
    for (int i = 0; i < RB; ++i)
        acc[i][0] = acc[i][1] = acc[i][2] = acc[i][3] = 0.f;

    const float2* Ht2 = reinterpret_cast<const float2*>(Ht);
    const float4* Wt4 = reinterpret_cast<const float4*>(Wt);

    for (int s = 0; s < KS; ++s) {
        __syncthreads();   // covers Ht stage (s=0) and Wt reuse (s>0)
        // stage Wt for k in [s*KR, s*KR+KR): lane-varying h -> conflict-free LDS writes
        for (int idx = t; idx < (KR / 4) * DOUT; idx += 256) {
            int h = idx % DOUT;
            int kq = idx / DOUT;
            float4 w = reinterpret_cast<const float4*>(W)[h * 32 + s * (KR / 4) + kq];
            int kk = 4 * kq;
            Wt[(kk + 0) * DOUT + h] = w.x;
            Wt[(kk + 1) * DOUT + h] = w.y;
            Wt[(kk + 2) * DOUT + h] = w.z;
            Wt[(kk + 3) * DOUT + h] = w.w;
        }
        __syncthreads();
#pragma unroll 4
        for (int k2 = 0; k2 < KR / 2; ++k2) {
            float4 w0 = Wt4[(2 * k2) * H4 + h4];
            float4 w1 = Wt4[(2 * k2 + 1) * H4 + h4];
#pragma unroll
            for (int i = 0; i < RB; ++i) {
                float2 hh = Ht2[(rg * RB + i) * 64 + s * (KR / 2) + k2];
                acc[i][0] += hh.x * w0.x + hh.y * w1.x;
                acc[i][1] += hh.x * w0.y + hh.y * w1.y;
                acc[i][2] += hh.x * w0.z + hh.y * w1.z;
                acc[i][3] += hh.x * w0.w + hh.y * w1.w;
            }
        }
    }

#pragma unroll
    for (int i = 0; i < RB; ++i) {
        int r = r0 + rg * RB + i;
        if (r >= n) continue;
        float4 o = make_float4(acc[i][0], acc[i][1], acc[i][2], acc[i][3]);
        if (FUSE) {
            float4 m = reinterpret_cast<const float4*>(mask)[(size_t)r * 32 + h4];
            o.x = fmaxf(o.x, 0.f) * m.x;
            o.y = fmaxf(o.y, 0.f) * m.y;
            o.z = fmaxf(o.z, 0.f) * m.z;
            o.w = fmaxf(o.w, 0.f) * m.w;
        }
        reinterpret_cast<float4*>(dst)[(size_t)r * H4 + h4] = o;
    }
}

// ---------------- launch ----------------

extern "C" void kernel_launch(void* const* d_in, const int* in_sizes, int n_in,
                              void* d_out, int out_size, void* d_ws, size_t ws_size,
                              hipStream_t stream) {
    const float* X = (const float*)d_in[0];
    const int* row = (const int*)d_in[1];
    const int* col = (const int*)d_in[2];
    const float* vals = (const float*)d_in[3];
    const float* W1 = (const float*)d_in[4];
    const float* W2 = (const float*)d_in[5];
    const float* mask = (const float*)d_in[6];
    float* out = (float*)d_out;

    const int N = in_sizes[0] / 128;  // 100000
    const int E = in_sizes[1];        // 1,700,000

    char* ws = (char*)d_ws;
    auto al = [](size_t x) { return (x + 511) & ~(size_t)511; };
    size_t off = 0;
    int* cursor = (int*)(ws + off);   off = al(off + (size_t)N * 4);      // counts then cursors
    int* starts = (int*)(ws + off);   off = al(off + (size_t)(N + 1) * 4);
    int* partial = (int*)(ws + off);  off = al(off + 512 * 4);
    int* adj_col = (int*)(ws + off);  off = al(off + (size_t)E * 4);
    float* adj_val = (float*)(ws + off); off = al(off + (size_t)E * 4);
    float* B1 = (float*)(ws + off);   off = al(off + (size_t)N * 128 * 4);
    float* B2 = (float*)(ws + off);   off = al(off + (size_t)N * 64 * 4);

    const int npart = (N + 255) / 256;  // 391 (<512)

    // --- CSR build ---
    hipMemsetAsync(cursor, 0, (size_t)N * 4, stream);
    k_hist<<<2048, 256, 0, stream>>>(row, cursor, E);
    k_part<<<npart, 256, 0, stream>>>(cursor, partial, N);
    k_scanpart<<<1, 512, 0, stream>>>(partial, npart, starts, N);
    k_starts<<<npart, 256, 0, stream>>>(cursor, partial, starts, cursor, N);
    k_scatter<<<2048, 256, 0, stream>>>(row, col, vals, cursor, adj_col, adj_val, E);

    // --- B1 = A' X ---
    k_spmm<128><<<(N + 1) / 2, 256, 0, stream>>>(starts, adj_col, adj_val, X, B1, N);
    // --- B1 = relu(B1 @ W1^T) * mask   (in-place, row tile staged first) ---
    k_gemm<128, 2, 4, true><<<(N + 31) / 32, 256, 0, stream>>>(B1, W1, mask, B1, N);
    // --- B2 = B1 @ W2^T ---
    k_gemm<64, 1, 2, false><<<(N + 31) / 32, 256, 0, stream>>>(B1, W2, nullptr, B2, N);
    // --- out = A' B2 ---
    k_spmm<64><<<(N + 3) / 4, 256, 0, stream>>>(starts, adj_col, adj_val, B2, out, N);
}

// Round 6
// 578.348 us; speedup vs baseline: 1.5763x; 1.5763x over previous
//
#include <hip/hip_runtime.h>
#include <hip/hip_fp16.h>

// GCN forward: out = (A' @ relu((A' @ X) @ W1^T) * mask) @ W2^T
// restructured:  B1 = A'Xh;  B1 = relu(B1 W1^T)*mask;  B2h = B1 W2^T (fp16);  out = A' B2h
// SpMM gathers fp16 operands (halved traffic/footprint), fp32 accumulate.
// R5 profile: spmm<128> 332us, VALU 24%, HBM 18% -> latency-bound; this round:
// 1-row-per-wave + 4-edge unroll (4x MLP), fp16 gathers, packed (col,val) adj.

typedef _Float16 half2_t __attribute__((ext_vector_type(2)));
typedef _Float16 half4_t __attribute__((ext_vector_type(4)));

// ---------------- fp32 -> fp16 convert (X) ----------------

__global__ __launch_bounds__(256) void k_f2h(const float4* __restrict__ in,
                                             half4_t* __restrict__ out, int n4) {
    int i = blockIdx.x * 256 + threadIdx.x;
    int stride = gridDim.x * 256;
    for (; i < n4; i += stride) {
        float4 v = in[i];
        half4_t h;
        h[0] = (_Float16)v.x; h[1] = (_Float16)v.y;
        h[2] = (_Float16)v.z; h[3] = (_Float16)v.w;
        out[i] = h;
    }
}

// ---------------- CSR build ----------------

__global__ __launch_bounds__(256) void k_hist(const int* __restrict__ row,
                                              int* __restrict__ counts, int E) {
    int i = blockIdx.x * blockDim.x + threadIdx.x;
    int stride = gridDim.x * blockDim.x;
    for (; i < E; i += stride) atomicAdd(&counts[row[i]], 1);
}

__global__ __launch_bounds__(256) void k_part(const int* __restrict__ counts,
                                              int* __restrict__ partial, int n) {
    __shared__ int s[256];
    int t = threadIdx.x;
    int i = blockIdx.x * 256 + t;
    s[t] = (i < n) ? counts[i] : 0;
    __syncthreads();
    for (int off = 128; off > 0; off >>= 1) {
        if (t < off) s[t] += s[t + off];
        __syncthreads();
    }
    if (t == 0) partial[blockIdx.x] = s[0];
}

__global__ __launch_bounds__(512) void k_scanpart(int* __restrict__ partial, int np,
                                                  int* __restrict__ starts, int N) {
    __shared__ int s[512];
    int t = threadIdx.x;
    int v = (t < np) ? partial[t] : 0;
    s[t] = v;
    __syncthreads();
    for (int off = 1; off < 512; off <<= 1) {
        int x = (t >= off) ? s[t - off] : 0;
        __syncthreads();
        s[t] += x;
        __syncthreads();
    }
    if (t < np) partial[t] = s[t] - v;   // exclusive
    if (t == 0) starts[N] = s[511];      // total = E
}

__global__ __launch_bounds__(256) void k_starts(const int* __restrict__ counts,
                                                const int* __restrict__ partial,
                                                int* __restrict__ starts,
                                                int* __restrict__ cursor, int n) {
    __shared__ int s[256];
    int t = threadIdx.x;
    int b = blockIdx.x;
    int i = b * 256 + t;
    int v = (i < n) ? counts[i] : 0;
    s[t] = v;
    __syncthreads();
    for (int off = 1; off < 256; off <<= 1) {
        int x = (t >= off) ? s[t - off] : 0;
        __syncthreads();
        s[t] += x;
        __syncthreads();
    }
    if (i < n) {
        int e = partial[b] + s[t] - v;
        starts[i] = e;
        cursor[i] = e;   // cursor aliases counts; same thread reads+writes i
    }
}

__global__ __launch_bounds__(256) void k_scatter(const int* __restrict__ row,
                                                 const int* __restrict__ col,
                                                 const float* __restrict__ vals,
                                                 int* __restrict__ cursor,
                                                 int2* __restrict__ adj, int E) {
    int i = blockIdx.x * blockDim.x + threadIdx.x;
    int stride = gridDim.x * blockDim.x;
    for (; i < E; i += stride) {
        int r = row[i];
        int p = atomicAdd(&cursor[r], 1);
        adj[p] = make_int2(col[i], __float_as_int(vals[i]));
    }
}

// ---------------- SpMM, fp16 gather / fp32 accumulate ----------------
// one row per 64-lane wave, 4 waves/block, 4-edge unroll for MLP.

// D=128: lane covers 2 consecutive cols (half2 = 4B gather per lane)
__global__ __launch_bounds__(256) void k_spmm128h(const int* __restrict__ starts,
                                                  const int2* __restrict__ adj,
                                                  const half2_t* __restrict__ src,
                                                  float* __restrict__ dst, int n) {
    const int lane = threadIdx.x & 63;
    const int r = blockIdx.x * 4 + (threadIdx.x >> 6);
    if (r >= n) return;
    int j = starts[r];
    const int j1 = starts[r + 1];
    float a0 = 0.f, a1 = 0.f;
    for (; j + 4 <= j1; j += 4) {
        int2 e0 = adj[j], e1 = adj[j + 1], e2 = adj[j + 2], e3 = adj[j + 3];
        half2_t g0 = src[(size_t)e0.x * 64 + lane];
        half2_t g1 = src[(size_t)e1.x * 64 + lane];
        half2_t g2 = src[(size_t)e2.x * 64 + lane];
        half2_t g3 = src[(size_t)e3.x * 64 + lane];
        float v0 = __int_as_float(e0.y), v1 = __int_as_float(e1.y);
        float v2 = __int_as_float(e2.y), v3 = __int_as_float(e3.y);
        a0 += v0 * (float)g0[0] + v1 * (float)g1[0] + v2 * (float)g2[0] + v3 * (float)g3[0];
        a1 += v0 * (float)g0[1] + v1 * (float)g1[1] + v2 * (float)g2[1] + v3 * (float)g3[1];
    }
    for (; j < j1; ++j) {
        int2 e = adj[j];
        half2_t g = src[(size_t)e.x * 64 + lane];
        float v = __int_as_float(e.y);
        a0 += v * (float)g[0];
        a1 += v * (float)g[1];
    }
    reinterpret_cast<float2*>(dst)[(size_t)r * 64 + lane] = make_float2(a0, a1);
}

// D=64: lane covers 1 col (2B gather per lane)
__global__ __launch_bounds__(256) void k_spmm64h(const int* __restrict__ starts,
                                                 const int2* __restrict__ adj,
                                                 const _Float16* __restrict__ src,
                                                 float* __restrict__ dst, int n) {
    const int lane = threadIdx.x & 63;
    const int r = blockIdx.x * 4 + (threadIdx.x >> 6);
    if (r >= n) return;
    int j = starts[r];
    const int j1 = starts[r + 1];
    float a = 0.f;
    for (; j + 4 <= j1; j += 4) {
        int2 e0 = adj[j], e1 = adj[j + 1], e2 = adj[j + 2], e3 = adj[j + 3];
        _Float16 g0 = src[(size_t)e0.x * 64 + lane];
        _Float16 g1 = src[(size_t)e1.x * 64 + lane];
        _Float16 g2 = src[(size_t)e2.x * 64 + lane];
        _Float16 g3 = src[(size_t)e3.x * 64 + lane];
        a += __int_as_float(e0.y) * (float)g0 + __int_as_float(e1.y) * (float)g1
           + __int_as_float(e2.y) * (float)g2 + __int_as_float(e3.y) * (float)g3;
    }
    for (; j < j1; ++j) {
        int2 e = adj[j];
        a += __int_as_float(e.y) * (float)src[(size_t)e.x * 64 + lane];
    }
    dst[(size_t)r * 64 + lane] = a;
}

// ---------------- dense GEMM: dst[n,DOUT] = src[n,128] @ W[DOUT,128]^T ----------------

template <int DOUT, int KS, int RB, bool FUSE, bool HOUT>
__global__ __launch_bounds__(256) void k_gemm(const float* __restrict__ src,
                                              const float* __restrict__ W,
                                              const float* __restrict__ mask,
                                              void* __restrict__ dst, int n) {
    constexpr int H4 = DOUT / 4;       // float4 groups along output dim
    constexpr int RG = 256 / H4;       // row groups
    constexpr int ROWS = RG * RB;      // rows per block (32)
    constexpr int KR = 128 / KS;       // k-rows resident per split
    __shared__ float Wt[KR * DOUT];
    __shared__ float Ht[ROWS * 128];

    const int t = threadIdx.x;
    const int r0 = blockIdx.x * ROWS;

    float4* Ht4 = reinterpret_cast<float4*>(Ht);
    for (int idx = t; idx < ROWS * 32; idx += 256) {
        int rr = idx >> 5, kq = idx & 31;
        int r = r0 + rr;
        float4 v = make_float4(0.f, 0.f, 0.f, 0.f);
        if (r < n) v = reinterpret_cast<const float4*>(src)[(size_t)r * 32 + kq];
        Ht4[idx] = v;
    }

    const int hq = t % H4;
    const int rg = t / H4;
    float acc[RB][4];
#pragma unroll
    for (int i = 0; i < RB; ++i)
        acc[i][0] = acc[i][1] = acc[i][2] = acc[i][3] = 0.f;

    const float2* Ht2 = reinterpret_cast<const float2*>(Ht);
    const float4* Wt4 = reinterpret_cast<const float4*>(Wt);

    for (int s = 0; s < KS; ++s) {
        __syncthreads();
        for (int idx = t; idx < (KR / 4) * DOUT; idx += 256) {
            int h = idx % DOUT;
            int kq = idx / DOUT;
            float4 w = reinterpret_cast<const float4*>(W)[h * 32 + s * (KR / 4) + kq];
            int kk = 4 * kq;
            Wt[(kk + 0) * DOUT + h] = w.x;
            Wt[(kk + 1) * DOUT + h] = w.y;
            Wt[(kk + 2) * DOUT + h] = w.z;
            Wt[(kk + 3) * DOUT + h] = w.w;
        }
        __syncthreads();
#pragma unroll 4
        for (int k2 = 0; k2 < KR / 2; ++k2) {
            float4 w0 = Wt4[(2 * k2) * H4 + hq];
            float4 w1 = Wt4[(2 * k2 + 1) * H4 + hq];
#pragma unroll
            for (int i = 0; i < RB; ++i) {
                float2 hh = Ht2[(rg * RB + i) * 64 + s * (KR / 2) + k2];
                acc[i][0] += hh.x * w0.x + hh.y * w1.x;
                acc[i][1] += hh.x * w0.y + hh.y * w1.y;
                acc[i][2] += hh.x * w0.z + hh.y * w1.z;
                acc[i][3] += hh.x * w0.w + hh.y * w1.w;
            }
        }
    }

#pragma unroll
    for (int i = 0; i < RB; ++i) {
        int r = r0 + rg * RB + i;
        if (r >= n) continue;
        float4 o = make_float4(acc[i][0], acc[i][1], acc[i][2], acc[i][3]);
        if (FUSE) {
            float4 m = reinterpret_cast<const float4*>(mask)[(size_t)r * 32 + hq];
            o.x = fmaxf(o.x, 0.f) * m.x;
            o.y = fmaxf(o.y, 0.f) * m.y;
            o.z = fmaxf(o.z, 0.f) * m.z;
            o.w = fmaxf(o.w, 0.f) * m.w;
        }
        if (HOUT) {
            half4_t h;
            h[0] = (_Float16)o.x; h[1] = (_Float16)o.y;
            h[2] = (_Float16)o.z; h[3] = (_Float16)o.w;
            reinterpret_cast<half4_t*>(dst)[(size_t)r * H4 + hq] = h;
        } else {
            reinterpret_cast<float4*>(dst)[(size_t)r * H4 + hq] = o;
        }
    }
}

// ---------------- launch ----------------

extern "C" void kernel_launch(void* const* d_in, const int* in_sizes, int n_in,
                              void* d_out, int out_size, void* d_ws, size_t ws_size,
                              hipStream_t stream) {
    const float* X = (const float*)d_in[0];
    const int* row = (const int*)d_in[1];
    const int* col = (const int*)d_in[2];
    const float* vals = (const float*)d_in[3];
    const float* W1 = (const float*)d_in[4];
    const float* W2 = (const float*)d_in[5];
    const float* mask = (const float*)d_in[6];
    float* out = (float*)d_out;

    const int N = in_sizes[0] / 128;  // 100000
    const int E = in_sizes[1];        // 1,700,000

    char* ws = (char*)d_ws;
    auto al = [](size_t x) { return (x + 511) & ~(size_t)511; };
    size_t off = 0;
    int* cursor = (int*)(ws + off);      off = al(off + (size_t)N * 4);
    int* starts = (int*)(ws + off);      off = al(off + (size_t)(N + 1) * 4);
    int* partial = (int*)(ws + off);     off = al(off + 512 * 4);
    int2* adj = (int2*)(ws + off);       off = al(off + (size_t)E * 8);
    float* B1 = (float*)(ws + off);      off = al(off + (size_t)N * 128 * 4);
    _Float16* Xh = (_Float16*)(ws + off);  off = al(off + (size_t)N * 128 * 2);
    _Float16* B2h = (_Float16*)(ws + off); off = al(off + (size_t)N * 64 * 2);

    const int npart = (N + 255) / 256;  // 391 (<512)

    // --- X -> fp16 ---
    k_f2h<<<2048, 256, 0, stream>>>((const float4*)X, (half4_t*)Xh, N * 32);

    // --- CSR build (packed (col,val) adjacency) ---
    hipMemsetAsync(cursor, 0, (size_t)N * 4, stream);
    k_hist<<<2048, 256, 0, stream>>>(row, cursor, E);
    k_part<<<npart, 256, 0, stream>>>(cursor, partial, N);
    k_scanpart<<<1, 512, 0, stream>>>(partial, npart, starts, N);
    k_starts<<<npart, 256, 0, stream>>>(cursor, partial, starts, cursor, N);
    k_scatter<<<2048, 256, 0, stream>>>(row, col, vals, cursor, adj, E);

    // --- B1 = A' Xh ---
    k_spmm128h<<<(N + 3) / 4, 256, 0, stream>>>(starts, adj, (const half2_t*)Xh, B1, N);
    // --- B1 = relu(B1 @ W1^T) * mask (in-place) ---
    k_gemm<128, 2, 4, true, false><<<(N + 31) / 32, 256, 0, stream>>>(B1, W1, mask, B1, N);
    // --- B2h = fp16(B1 @ W2^T) ---
    k_gemm<64, 1, 2, false, true><<<(N + 31) / 32, 256, 0, stream>>>(B1, W2, nullptr, B2h, N);
    // --- out = A' B2h ---
    k_spmm64h<<<(N + 3) / 4, 256, 0, stream>>>(starts, adj, B2h, out, N);
}